// Round 13
// baseline (180.031 us; speedup 1.0000x reference)
//
#include <hip/hip_runtime.h>
#include <hip/hip_fp16.h>
#include <stdint.h>

// ---- types ----
typedef _Float16 h16;
typedef _Float16 h16x8 __attribute__((ext_vector_type(8)));
typedef float f32x4 __attribute__((ext_vector_type(4)));

#define BB 4
#define SS 2048
#define DD 1024

// epilogue modes
#define EPI_H16 0   // store fp16 C
#define EPI_EXP 1   // store fp16 exp(C - 16)   (unnormalized softmax numerator)
#define EPI_DIV 2   // store fp32 C * rsum[row] (rsum = reciprocal row sums)

__device__ __forceinline__ void gload16(const void* g, void* l) {
    __builtin_amdgcn_global_load_lds(
        (const __attribute__((address_space(1))) uint32_t*)g,
        (__attribute__((address_space(3))) uint32_t*)l, 16, 0, 0);
}

// ---- fused fp32 -> fp16 convert; every instruction wave-coalesced ----
__global__ __launch_bounds__(256) void cvt_all(
    const float* __restrict__ q, const float* __restrict__ k,
    const float* __restrict__ v, const float* __restrict__ w,
    h16* __restrict__ qh, h16* __restrict__ kh,
    h16* __restrict__ vh, h16* __restrict__ wh) {
    int b = blockIdx.x;
    const float* src; h16* dst; float sc = 1.0f;
    if (b < 2048)      { src = q; dst = qh; sc = 0.125f; }
    else if (b < 4096) { src = k; dst = kh; b -= 2048; }
    else if (b < 6144) { src = v; dst = vh; b -= 4096; }
    else               { src = w; dst = wh; b -= 6144; }
    size_t base = (size_t)b * 1024 + threadIdx.x;   // float4 index
#pragma unroll
    for (int i = 0; i < 4; ++i) {
        size_t g = base + (size_t)i * 256;
        float4 a = ((const float4*)src)[g];
        union { int2 i2; h16 h[4]; } u;
        u.h[0] = (h16)(a.x * sc); u.h[1] = (h16)(a.y * sc);
        u.h[2] = (h16)(a.z * sc); u.h[3] = (h16)(a.w * sc);
        ((int2*)dst)[g] = u.i2;
    }
}

// ==== A-direct big GEMM (vmcnt(0) sync — no counted ledger): ====
// BM=256 BN=256 BK=64, 512 thr, 8 waves (2Mx4N), wave tile 128x64.
// A: global->register direct (wave-private; A never touches LDS) -> LDS
// carries only B (stage 32KB + frag reads 64KB per CU-K-tile vs ~620cy
// MFMA -> LDS cap lifted from 62% to ~100%). A-regs half-rotated: refill
// set0 between the two MFMA halves; only the last 8 loads' L2 latency is
// exposed at the per-K-tile vmcnt(0) drain. All register deps compiler-
// managed; the ONLY hand sync is vmcnt(0)+barrier once per K-tile.
template<int EPI>
__global__ __launch_bounds__(512, 2) void gemm_adz(
    const h16* __restrict__ A, const h16* __restrict__ B, void* __restrict__ Cv,
    int lda, int ldb, int ldc, int K, int tilesN, int tilesMN,
    long long aBatch, long long bBatch, long long cBatch, const float* __restrict__ rsum)
{
    constexpr int BBYT = 256 * 64 * 2;   // 32 KB B tile
    __shared__ __align__(1024) char lds[2 * BBYT];   // 64 KB

    const int tid = threadIdx.x;
    const int nwg = gridDim.x;
    const int bid = blockIdx.x;
    const int wgid = (bid & 7) * (nwg >> 3) + (bid >> 3);   // XCD swizzle
    const int bb  = wgid / tilesMN;
    const int rem = wgid % tilesMN;
    const int tm = rem / tilesN, tn = rem % tilesN;
    const int row0 = tm * 256, col0 = tn * 256;

    const h16* Ab = A + (long long)bb * aBatch;
    const h16* Bb = B + (long long)bb * bBatch;

    const int lane = tid & 63, wid = tid >> 6;
    const int wm = wid >> 2, wn = wid & 3;     // 2M x 4N, wave tile 128x64
    const int frow = lane & 15, kq = lane >> 4;

    const int NT = K >> 6;

    f32x4 acc[8][4];
#pragma unroll
    for (int m = 0; m < 8; ++m)
#pragma unroll
        for (int n = 0; n < 4; ++n) acc[m][n] = (f32x4){0.f, 0.f, 0.f, 0.f};

    char* l0 = (char*)lds;

    auto STAGE_B = [&](int kt, int buf) {
#pragma unroll
        for (int i = 0; i < 4; ++i) {
            int d = i * 512 + tid;
            int s = d & 7, r = d >> 3;
            int gg = s ^ (r & 7);
            gload16(Bb + (size_t)(col0 + r) * ldb + kt + gg * 8,
                    l0 + buf * BBYT + (r * 8 + s) * 16);
        }
    };
    h16x8 af[16];   // frag (mm,ks) -> af[mm*2+ks]; set0 = mm 0..3, set1 = mm 4..7
    auto LOAD_A_H = [&](int kt, int mh) {
#pragma unroll
        for (int mm = 0; mm < 4; ++mm)
#pragma unroll
            for (int ks = 0; ks < 2; ++ks) {
                int r = row0 + wm * 128 + (mh * 4 + mm) * 16 + frow;
                af[(mh * 4 + mm) * 2 + ks] =
                    *(const h16x8*)(Ab + (size_t)r * lda + kt + (ks * 4 + kq) * 8);
            }
    };
    h16x8 bf[4][2];
    auto READ_B = [&](int buf) {
#pragma unroll
        for (int nn = 0; nn < 4; ++nn)
#pragma unroll
            for (int ks = 0; ks < 2; ++ks) {
                int r = wn * 64 + nn * 16 + frow;
                int s = (ks * 4 + kq) ^ (r & 7);
                bf[nn][ks] = *(const h16x8*)(l0 + buf * BBYT + (r * 8 + s) * 16);
            }
    };
    auto MFMA_H = [&](int mh) {
        __builtin_amdgcn_s_setprio(1);
#pragma unroll
        for (int mm = 0; mm < 4; ++mm)
#pragma unroll
            for (int nn = 0; nn < 4; ++nn)
#pragma unroll
                for (int ks = 0; ks < 2; ++ks)
                    acc[mh * 4 + mm][nn] = __builtin_amdgcn_mfma_f32_16x16x32_f16(
                        af[(mh * 4 + mm) * 2 + ks], bf[nn][ks], acc[mh * 4 + mm][nn], 0, 0, 0);
        __builtin_amdgcn_s_setprio(0);
    };

    // ---- prologue: stage B(0); A(0) into regs; full drain
    STAGE_B(0, 0);
    LOAD_A_H(0, 0); LOAD_A_H(0, 1);
    asm volatile("s_waitcnt vmcnt(0)" ::: "memory");
    __builtin_amdgcn_s_barrier();

    for (int G = 0; G < NT; ++G) {
        const int buf = G & 1;
        const int kt1 = (G + 1) << 6;
        if (G + 1 < NT) STAGE_B(kt1, buf ^ 1);   // issue-early into free buffer
        READ_B(buf);
        MFMA_H(0);                               // uses af set0 (+bf)
        if (G + 1 < NT) LOAD_A_H(kt1, 0);        // refill set0 under MFMA_H(1)
        MFMA_H(1);                               // uses af set1
        if (G + 1 < NT) {
            LOAD_A_H(kt1, 1);                    // refill set1 (exposed at drain)
            asm volatile("s_waitcnt vmcnt(0)" ::: "memory");   // everything resident
            __builtin_amdgcn_s_barrier();
        }
    }

    // ---- epilogue: C/D layout col=lane&15, row=(lane>>4)*4+j
    const int erow = row0 + wm * 128 + (lane >> 4) * 4;
    const int ecol = col0 + wn * 64 + (lane & 15);
#pragma unroll
    for (int m = 0; m < 8; ++m)
#pragma unroll
        for (int n = 0; n < 4; ++n)
#pragma unroll
            for (int j = 0; j < 4; ++j) {
                int row = erow + m * 16 + j, col = ecol + n * 16;
                float vv = acc[m][n][j];
                if constexpr (EPI == EPI_EXP) {
                    h16* C = (h16*)Cv + (long long)bb * cBatch;
                    C[(size_t)row * ldc + col] = (h16)__expf(vv - 16.0f);
                } else if constexpr (EPI == EPI_DIV) {
                    float* C = (float*)Cv + (long long)bb * cBatch;
                    C[(size_t)row * ldc + col] = vv * rsum[bb * SS + row];
                } else {
                    h16* C = (h16*)Cv + (long long)bb * cBatch;
                    C[(size_t)row * ldc + col] = (h16)vv;
                }
            }
}

// ==== small GEMM (round-6/12 verified): 128x128, 4 waves, 2 blocks/CU ====
template<int EPI>
__global__ __launch_bounds__(256, 2) void gemm2p_sm(
    const h16* __restrict__ A, const h16* __restrict__ B, void* __restrict__ Cv,
    int lda, int ldb, int ldc, int K, int tilesN, int tilesMN,
    long long aBatch, long long bBatch, long long cBatch, const float* __restrict__ rsum)
{
    constexpr int ABYTES = 128 * 128;
    constexpr int BBYTES = 128 * 128;
    constexpr int BUFB   = ABYTES + BBYTES;

    __shared__ __align__(1024) char lds[2 * BUFB];   // 64 KB

    const int tid = threadIdx.x;
    const int nwg = gridDim.x;
    const int bid = blockIdx.x;
    const int wgid = (bid & 7) * (nwg >> 3) + (bid >> 3);   // XCD swizzle
    const int bb  = wgid / tilesMN;
    const int rem = wgid % tilesMN;
    const int tm = rem / tilesN, tn = rem % tilesN;
    const int row0 = tm * 128, col0 = tn * 128;

    const h16* Ab = A + (long long)bb * aBatch;
    const h16* Bb = B + (long long)bb * bBatch;

    const int lane = tid & 63, wid = tid >> 6;
    const int wm = wid >> 1, wn = wid & 1;     // 2M x 2N, wave tile 64x64
    const int frow = lane & 15, kq = lane >> 4;

    const int NT = K >> 6;

    f32x4 acc[4][4];
#pragma unroll
    for (int m = 0; m < 4; ++m)
#pragma unroll
        for (int n = 0; n < 4; ++n) acc[m][n] = (f32x4){0.f, 0.f, 0.f, 0.f};

    char* l0 = (char*)lds;

    auto STAGE_B = [&](int kt, int buf) {
#pragma unroll
        for (int i = 0; i < 4; ++i) {
            int d = i * 256 + tid;
            int s = d & 7, r = d >> 3;
            int gg = s ^ (r & 7);
            gload16(Bb + (size_t)(col0 + r) * ldb + kt + gg * 8,
                    l0 + buf * BUFB + ABYTES + (r * 8 + s) * 16);
        }
    };
    auto STAGE_AH = [&](int kt, int buf, int mh) {
#pragma unroll
        for (int i = 0; i < 2; ++i) {
            int d = i * 256 + tid;
            int s = d & 7, hr = d >> 3;
            int r = ((hr & ~31) << 1) + mh * 32 + (hr & 31);
            int gg = s ^ (r & 7);
            gload16(Ab + (size_t)(row0 + r) * lda + kt + gg * 8,
                    l0 + buf * BUFB + (r * 8 + s) * 16);
        }
    };
    auto READ_A = [&](int buf, int mh, h16x8 (&af)[2][2]) {
#pragma unroll
        for (int mm = 0; mm < 2; ++mm)
#pragma unroll
            for (int ks = 0; ks < 2; ++ks) {
                int r = wm * 64 + (mh * 2 + mm) * 16 + frow;
                int s = (ks * 4 + kq) ^ (r & 7);
                af[mm][ks] = *(const h16x8*)(l0 + buf * BUFB + (r * 8 + s) * 16);
            }
    };
    auto READ_B = [&](int buf, h16x8 (&bf)[4][2]) {
#pragma unroll
        for (int nn = 0; nn < 4; ++nn)
#pragma unroll
            for (int ks = 0; ks < 2; ++ks) {
                int r = wn * 64 + nn * 16 + frow;
                int s = (ks * 4 + kq) ^ (r & 7);
                bf[nn][ks] = *(const h16x8*)(l0 + buf * BUFB + ABYTES + (r * 8 + s) * 16);
            }
    };
    auto MFMA_H = [&](int mh, h16x8 (&af)[2][2], h16x8 (&bf)[4][2]) {
        __builtin_amdgcn_s_setprio(1);
#pragma unroll
        for (int ks = 0; ks < 2; ++ks)
#pragma unroll
            for (int mm = 0; mm < 2; ++mm)
#pragma unroll
                for (int nn = 0; nn < 4; ++nn)
                    acc[mh * 2 + mm][nn] =
                        __builtin_amdgcn_mfma_f32_16x16x32_f16(
                            af[mm][ks], bf[nn][ks], acc[mh * 2 + mm][nn], 0, 0, 0);
        __builtin_amdgcn_s_setprio(0);
    };

    STAGE_B(0, 0); STAGE_AH(0, 0, 0); STAGE_AH(0, 0, 1);
    asm volatile("s_waitcnt vmcnt(2)" ::: "memory");
    __builtin_amdgcn_s_barrier();

    h16x8 af[2][2], bf[4][2];

    for (int G = 0; G < NT; ++G) {
        const int buf = G & 1;
        const int kt1 = (G + 1) << 6;
        if (G + 1 < NT) {
            STAGE_B(kt1, buf ^ 1);
            STAGE_AH(kt1, buf ^ 1, 0);
            STAGE_AH(kt1, buf ^ 1, 1);
        }
        READ_A(buf, 0, af);
        READ_B(buf, bf);
        MFMA_H(0, af, bf);
        if (G + 1 < NT) asm volatile("s_waitcnt vmcnt(8)" ::: "memory");
        else            asm volatile("s_waitcnt vmcnt(0)" ::: "memory");
        __builtin_amdgcn_s_barrier();
        READ_A(buf, 1, af);
        MFMA_H(1, af, bf);
        if (G + 1 >= NT) break;
        asm volatile("s_waitcnt vmcnt(2)" ::: "memory");
        __builtin_amdgcn_s_barrier();
    }

    const int erow = row0 + wm * 64 + (lane >> 4) * 4;
    const int ecol = col0 + wn * 64 + (lane & 15);
#pragma unroll
    for (int m = 0; m < 4; ++m)
#pragma unroll
        for (int n = 0; n < 4; ++n)
#pragma unroll
            for (int j = 0; j < 4; ++j) {
                int row = erow + m * 16 + j, col = ecol + n * 16;
                float vv = acc[m][n][j];
                if constexpr (EPI == EPI_DIV) {
                    float* C = (float*)Cv + (long long)bb * cBatch;
                    C[(size_t)row * ldc + col] = vv * rsum[bb * SS + row];
                } else if constexpr (EPI == EPI_EXP) {
                    h16* C = (h16*)Cv + (long long)bb * cBatch;
                    C[(size_t)row * ldc + col] = (h16)__expf(vv - 16.0f);
                } else {
                    h16* C = (h16*)Cv + (long long)bb * cBatch;
                    C[(size_t)row * ldc + col] = (h16)vv;
                }
            }
}

// ---- reciprocal row sums of E (fp16 rows of length 2048); one block/row ----
__global__ __launch_bounds__(256) void rowsumE(const h16* __restrict__ sc,
                                               float* __restrict__ rsum) {
    const int row = blockIdx.x;
    const h16* rp = sc + (size_t)row * 2048;
    union { int4 i4; h16 h[8]; } u;
    u.i4 = ((const int4*)rp)[threadIdx.x];
    float s = 0.f;
#pragma unroll
    for (int j = 0; j < 8; ++j) s += (float)u.h[j];
#pragma unroll
    for (int off = 32; off; off >>= 1) s += __shfl_xor(s, off);
    __shared__ float ws[4];
    const int lane = threadIdx.x & 63, wid = threadIdx.x >> 6;
    if (lane == 0) ws[wid] = s;
    __syncthreads();
    if (threadIdx.x == 0)
        rsum[row] = 1.0f / (ws[0] + ws[1] + ws[2] + ws[3]);
}

extern "C" void kernel_launch(void* const* d_in, const int* in_sizes, int n_in,
                              void* d_out, int out_size, void* d_ws, size_t ws_size,
                              hipStream_t stream) {
    (void)in_sizes; (void)n_in; (void)out_size; (void)ws_size;
    const float* q = (const float*)d_in[0];
    const float* k = (const float*)d_in[1];
    const float* v = (const float*)d_in[2];
    const float* w = (const float*)d_in[3];
    float* out = (float*)d_out;

    const size_t QKV = (size_t)BB * SS * DD;
    h16* qh = (h16*)d_ws;            // 16 MB (reused as vpT after GEMM1 consumes q)
    h16* kh = qh + QKV;              // 16 MB
    h16* vh = kh + QKV;              // 16 MB
    h16* wh = vh + QKV;              // 2 MB
    h16* sc = wh + (size_t)DD * DD;  // E = exp(scores-16): 33.5 MB
    float* rsum = (float*)(sc + (size_t)BB * SS * SS);   // 32 KB reciprocal sums

    // 1) fused fp32 -> fp16 (scale 1/sqrt(64)=0.125 folded into q)
    cvt_all<<<6400, 256, 0, stream>>>(q, k, v, w, qh, kh, vh, wh);

    // 2) GEMM1 (A-direct, vmcnt0) + exp epilogue: E = exp(q.k - 16)
    //    256x256 tiles: 8x8x4 = 256 wgs (1 block/CU)
    gemm_adz<EPI_EXP><<<256, 512, 0, stream>>>(
        qh, kh, (void*)sc, DD, DD, SS, DD, /*tilesN=*/8, /*tilesMN=*/64,
        (long long)SS * DD, (long long)SS * DD, (long long)SS * SS, nullptr);

    // 3) reciprocal row sums (read-only)
    rowsumE<<<BB * SS, 256, 0, stream>>>(sc, rsum);

    // 4) GEMM2 (control): vpT[e][s] = sum_d W[e,d]*V[s,d]; 128^2 tiles, 512 wgs
    h16* vpT = qh;
    gemm2p_sm<EPI_H16><<<512, 256, 0, stream>>>(
        wh, vh, (void*)vpT, DD, DD, BB * SS, DD, /*tilesN=*/64, /*tilesMN=*/512,
        0LL, 0LL, 0LL, nullptr);

    // 5) GEMM3 (control) + normalize: Y = (E . vpT) * rsum
    gemm2p_sm<EPI_DIV><<<512, 256, 0, stream>>>(
        sc, vpT, (void*)out, SS, BB * SS, DD, SS, /*tilesN=*/8, /*tilesMN=*/128,
        (long long)SS * SS, (long long)SS, (long long)SS * DD, rsum);
}

// Round 14
// 134.603 us; speedup vs baseline: 1.3375x; 1.3375x over previous
//
#include <hip/hip_runtime.h>
#include <hip/hip_fp16.h>
#include <stdint.h>

// ---- types ----
typedef _Float16 h16;
typedef _Float16 h16x8 __attribute__((ext_vector_type(8)));
typedef float f32x4 __attribute__((ext_vector_type(4)));

#define BB 4
#define SS 2048
#define DD 1024

// epilogue modes
#define EPI_H16 0   // store fp16 C
#define EPI_EXP 1   // store fp16 exp(C - 16)   (unnormalized softmax numerator)
#define EPI_DIV 2   // store fp32 C * rsum[row] (rsum = reciprocal row sums)

__device__ __forceinline__ void gload16(const void* g, void* l) {
    __builtin_amdgcn_global_load_lds(
        (const __attribute__((address_space(1))) uint32_t*)g,
        (__attribute__((address_space(3))) uint32_t*)l, 16, 0, 0);
}

// ---- fused fp32 -> fp16 convert; 8-deep MLP: all 8 loads issued before
// any store (probe: is the 3.7 TB/s wall MLP-limited?). 3200 blocks exact:
// q 1024, k 1024, v 1024, W 128. 2048 float4 per block.
__global__ __launch_bounds__(256) void cvt_all(
    const float* __restrict__ q, const float* __restrict__ k,
    const float* __restrict__ v, const float* __restrict__ w,
    h16* __restrict__ qh, h16* __restrict__ kh,
    h16* __restrict__ vh, h16* __restrict__ wh) {
    int b = blockIdx.x;
    const float* src; h16* dst; float sc = 1.0f;
    if (b < 1024)      { src = q; dst = qh; sc = 0.125f; }
    else if (b < 2048) { src = k; dst = kh; b -= 1024; }
    else if (b < 3072) { src = v; dst = vh; b -= 2048; }
    else               { src = w; dst = wh; b -= 3072; }
    size_t base = (size_t)b * 2048 + threadIdx.x;   // float4 index
    float4 a[8];
#pragma unroll
    for (int i = 0; i < 8; ++i) a[i] = ((const float4*)src)[base + (size_t)i * 256];
#pragma unroll
    for (int i = 0; i < 8; ++i) {
        union { int2 i2; h16 h[4]; } u;
        u.h[0] = (h16)(a[i].x * sc); u.h[1] = (h16)(a[i].y * sc);
        u.h[2] = (h16)(a[i].z * sc); u.h[3] = (h16)(a[i].w * sc);
        ((int2*)dst)[base + (size_t)i * 256] = u.i2;
    }
}

// ==== 2-phase bt-form GEMM, BM=256/BN=256, 8 waves, 1 block/CU ====
// (round-12 verified; counted-vmcnt ledger over homogeneous gload_lds queue)
template<int BM, int EPI>
__global__ __launch_bounds__(512, 2) void gemm2p(
    const h16* __restrict__ A, const h16* __restrict__ B, void* __restrict__ Cv,
    int lda, int ldb, int ldc, int K, int tilesN, int tilesMN,
    long long aBatch, long long bBatch, long long cBatch, const float* __restrict__ rsum)
{
    constexpr int WROWS  = BM / 2;
    constexpr int MF     = WROWS / 16;
    constexpr int MH     = MF / 2;
    constexpr int AH     = WROWS / 2;
    constexpr int AL     = BM / 128;
    constexpr int ABYTES = BM * 128;
    constexpr int BBYTES = 256 * 128;
    constexpr int BUFB   = ABYTES + BBYTES;

    __shared__ __align__(1024) char lds[2 * BUFB];

    const int tid = threadIdx.x;
    const int nwg = gridDim.x;
    const int bid = blockIdx.x;
    const int wgid = (bid & 7) * (nwg >> 3) + (bid >> 3);
    const int bb  = wgid / tilesMN;
    const int rem = wgid % tilesMN;
    const int tm = rem / tilesN, tn = rem % tilesN;
    const int row0 = tm * BM, col0 = tn * 256;

    const h16* Ab = A + (long long)bb * aBatch;
    const h16* Bb = B + (long long)bb * bBatch;

    const int lane = tid & 63, wid = tid >> 6;
    const int wm = wid >> 2, wn = wid & 3;
    const int frow = lane & 15, kq = lane >> 4;

    const int NT = K >> 6;

    f32x4 acc[MF][4];
#pragma unroll
    for (int m = 0; m < MF; ++m)
#pragma unroll
        for (int n = 0; n < 4; ++n) acc[m][n] = (f32x4){0.f, 0.f, 0.f, 0.f};

    char* l0 = (char*)lds;

    auto STAGE_B = [&](int kt, int buf) {
#pragma unroll
        for (int i = 0; i < 4; ++i) {
            int d = i * 512 + tid;
            int s = d & 7, r = d >> 3;
            int gg = s ^ (r & 7);
            gload16(Bb + (size_t)(col0 + r) * ldb + kt + gg * 8,
                    l0 + buf * BUFB + ABYTES + (r * 8 + s) * 16);
        }
    };
    auto STAGE_AH = [&](int kt, int buf, int mh) {
#pragma unroll
        for (int i = 0; i < AL; ++i) {
            int d = i * 512 + tid;
            int s = d & 7, hr = d >> 3;
            int r = ((hr & ~(AH - 1)) << 1) + mh * AH + (hr & (AH - 1));
            int gg = s ^ (r & 7);
            gload16(Ab + (size_t)(row0 + r) * lda + kt + gg * 8,
                    l0 + buf * BUFB + (r * 8 + s) * 16);
        }
    };
    auto READ_A = [&](int buf, int mh, h16x8 (&af)[MH][2]) {
#pragma unroll
        for (int mm = 0; mm < MH; ++mm)
#pragma unroll
            for (int ks = 0; ks < 2; ++ks) {
                int r = wm * WROWS + (mh * MH + mm) * 16 + frow;
                int s = (ks * 4 + kq) ^ (r & 7);
                af[mm][ks] = *(const h16x8*)(l0 + buf * BUFB + (r * 8 + s) * 16);
            }
    };
    auto READ_B = [&](int buf, h16x8 (&bf)[4][2]) {
#pragma unroll
        for (int nn = 0; nn < 4; ++nn)
#pragma unroll
            for (int ks = 0; ks < 2; ++ks) {
                int r = wn * 64 + nn * 16 + frow;
                int s = (ks * 4 + kq) ^ (r & 7);
                bf[nn][ks] = *(const h16x8*)(l0 + buf * BUFB + ABYTES + (r * 8 + s) * 16);
            }
    };
    auto MFMA_H = [&](int mh, h16x8 (&af)[MH][2], h16x8 (&bf)[4][2]) {
        __builtin_amdgcn_s_setprio(1);
#pragma unroll
        for (int ks = 0; ks < 2; ++ks)
#pragma unroll
            for (int mm = 0; mm < MH; ++mm)
#pragma unroll
                for (int nn = 0; nn < 4; ++nn)
                    acc[mh * MH + mm][nn] =
                        __builtin_amdgcn_mfma_f32_16x16x32_f16(
                            af[mm][ks], bf[nn][ks], acc[mh * MH + mm][nn], 0, 0, 0);
        __builtin_amdgcn_s_setprio(0);
    };

    STAGE_B(0, 0); STAGE_AH(0, 0, 0); STAGE_AH(0, 0, 1);
    if constexpr (BM == 256) asm volatile("s_waitcnt vmcnt(2)" ::: "memory");
    else                     asm volatile("s_waitcnt vmcnt(1)" ::: "memory");
    __builtin_amdgcn_s_barrier();

    h16x8 af[MH][2], bf[4][2];

    for (int G = 0; G < NT; ++G) {
        const int buf = G & 1;
        const int kt1 = (G + 1) << 6;
        if (G + 1 < NT) {
            STAGE_B(kt1, buf ^ 1);
            STAGE_AH(kt1, buf ^ 1, 0);
            STAGE_AH(kt1, buf ^ 1, 1);
        }
        READ_A(buf, 0, af);
        READ_B(buf, bf);
        MFMA_H(0, af, bf);
        if (G + 1 < NT) {
            if constexpr (BM == 256) asm volatile("s_waitcnt vmcnt(8)" ::: "memory");
            else                     asm volatile("s_waitcnt vmcnt(6)" ::: "memory");
        } else {
            asm volatile("s_waitcnt vmcnt(0)" ::: "memory");
        }
        __builtin_amdgcn_s_barrier();
        READ_A(buf, 1, af);
        MFMA_H(1, af, bf);
        if (G + 1 >= NT) break;
        if constexpr (BM == 256) asm volatile("s_waitcnt vmcnt(2)" ::: "memory");
        else                     asm volatile("s_waitcnt vmcnt(1)" ::: "memory");
        __builtin_amdgcn_s_barrier();
    }

    // ---- epilogue: C/D layout col=lane&15, row=(lane>>4)*4+j
    const int erow = row0 + wm * WROWS + (lane >> 4) * 4;
    const int ecol = col0 + wn * 64 + (lane & 15);
#pragma unroll
    for (int m = 0; m < MF; ++m)
#pragma unroll
        for (int n = 0; n < 4; ++n)
#pragma unroll
            for (int j = 0; j < 4; ++j) {
                int row = erow + m * 16 + j, col = ecol + n * 16;
                float vv = acc[m][n][j];
                if constexpr (EPI == EPI_EXP) {
                    h16* C = (h16*)Cv + (long long)bb * cBatch;
                    C[(size_t)row * ldc + col] = (h16)__expf(vv - 16.0f);
                } else if constexpr (EPI == EPI_DIV) {
                    float* C = (float*)Cv + (long long)bb * cBatch;
                    C[(size_t)row * ldc + col] = vv * rsum[bb * SS + row];
                } else {
                    h16* C = (h16*)Cv + (long long)bb * cBatch;
                    C[(size_t)row * ldc + col] = (h16)vv;
                }
            }
}

// ==== small GEMM: 128x128 tile, 4 waves (2Mx2N), 256 thr, 64KB LDS ====
// 2 blocks/CU (round-6/12 verified)
template<int EPI>
__global__ __launch_bounds__(256, 2) void gemm2p_sm(
    const h16* __restrict__ A, const h16* __restrict__ B, void* __restrict__ Cv,
    int lda, int ldb, int ldc, int K, int tilesN, int tilesMN,
    long long aBatch, long long bBatch, long long cBatch, const float* __restrict__ rsum)
{
    constexpr int ABYTES = 128 * 128;
    constexpr int BBYTES = 128 * 128;
    constexpr int BUFB   = ABYTES + BBYTES;

    __shared__ __align__(1024) char lds[2 * BUFB];   // 64 KB

    const int tid = threadIdx.x;
    const int nwg = gridDim.x;
    const int bid = blockIdx.x;
    const int wgid = (bid & 7) * (nwg >> 3) + (bid >> 3);   // XCD swizzle
    const int bb  = wgid / tilesMN;
    const int rem = wgid % tilesMN;
    const int tm = rem / tilesN, tn = rem % tilesN;
    const int row0 = tm * 128, col0 = tn * 128;

    const h16* Ab = A + (long long)bb * aBatch;
    const h16* Bb = B + (long long)bb * bBatch;

    const int lane = tid & 63, wid = tid >> 6;
    const int wm = wid >> 1, wn = wid & 1;     // 2M x 2N, wave tile 64x64
    const int frow = lane & 15, kq = lane >> 4;

    const int NT = K >> 6;

    f32x4 acc[4][4];
#pragma unroll
    for (int m = 0; m < 4; ++m)
#pragma unroll
        for (int n = 0; n < 4; ++n) acc[m][n] = (f32x4){0.f, 0.f, 0.f, 0.f};

    char* l0 = (char*)lds;

    auto STAGE_B = [&](int kt, int buf) {
#pragma unroll
        for (int i = 0; i < 4; ++i) {
            int d = i * 256 + tid;
            int s = d & 7, r = d >> 3;
            int gg = s ^ (r & 7);
            gload16(Bb + (size_t)(col0 + r) * ldb + kt + gg * 8,
                    l0 + buf * BUFB + ABYTES + (r * 8 + s) * 16);
        }
    };
    auto STAGE_AH = [&](int kt, int buf, int mh) {
#pragma unroll
        for (int i = 0; i < 2; ++i) {
            int d = i * 256 + tid;
            int s = d & 7, hr = d >> 3;
            int r = ((hr & ~31) << 1) + mh * 32 + (hr & 31);
            int gg = s ^ (r & 7);
            gload16(Ab + (size_t)(row0 + r) * lda + kt + gg * 8,
                    l0 + buf * BUFB + (r * 8 + s) * 16);
        }
    };
    auto READ_A = [&](int buf, int mh, h16x8 (&af)[2][2]) {
#pragma unroll
        for (int mm = 0; mm < 2; ++mm)
#pragma unroll
            for (int ks = 0; ks < 2; ++ks) {
                int r = wm * 64 + (mh * 2 + mm) * 16 + frow;
                int s = (ks * 4 + kq) ^ (r & 7);
                af[mm][ks] = *(const h16x8*)(l0 + buf * BUFB + (r * 8 + s) * 16);
            }
    };
    auto READ_B = [&](int buf, h16x8 (&bf)[4][2]) {
#pragma unroll
        for (int nn = 0; nn < 4; ++nn)
#pragma unroll
            for (int ks = 0; ks < 2; ++ks) {
                int r = wn * 64 + nn * 16 + frow;
                int s = (ks * 4 + kq) ^ (r & 7);
                bf[nn][ks] = *(const h16x8*)(l0 + buf * BUFB + ABYTES + (r * 8 + s) * 16);
            }
    };
    auto MFMA_H = [&](int mh, h16x8 (&af)[2][2], h16x8 (&bf)[4][2]) {
        __builtin_amdgcn_s_setprio(1);
#pragma unroll
        for (int ks = 0; ks < 2; ++ks)
#pragma unroll
            for (int mm = 0; mm < 2; ++mm)
#pragma unroll
                for (int nn = 0; nn < 4; ++nn)
                    acc[mh * 2 + mm][nn] =
                        __builtin_amdgcn_mfma_f32_16x16x32_f16(
                            af[mm][ks], bf[nn][ks], acc[mh * 2 + mm][nn], 0, 0, 0);
        __builtin_amdgcn_s_setprio(0);
    };

    STAGE_B(0, 0); STAGE_AH(0, 0, 0); STAGE_AH(0, 0, 1);
    asm volatile("s_waitcnt vmcnt(2)" ::: "memory");
    __builtin_amdgcn_s_barrier();

    h16x8 af[2][2], bf[4][2];

    for (int G = 0; G < NT; ++G) {
        const int buf = G & 1;
        const int kt1 = (G + 1) << 6;
        if (G + 1 < NT) {
            STAGE_B(kt1, buf ^ 1);
            STAGE_AH(kt1, buf ^ 1, 0);
            STAGE_AH(kt1, buf ^ 1, 1);
        }
        READ_A(buf, 0, af);
        READ_B(buf, bf);
        MFMA_H(0, af, bf);
        if (G + 1 < NT) asm volatile("s_waitcnt vmcnt(8)" ::: "memory");
        else            asm volatile("s_waitcnt vmcnt(0)" ::: "memory");
        __builtin_amdgcn_s_barrier();
        READ_A(buf, 1, af);
        MFMA_H(1, af, bf);
        if (G + 1 >= NT) break;
        asm volatile("s_waitcnt vmcnt(2)" ::: "memory");
        __builtin_amdgcn_s_barrier();
    }

    const int erow = row0 + wm * 64 + (lane >> 4) * 4;
    const int ecol = col0 + wn * 64 + (lane & 15);
#pragma unroll
    for (int m = 0; m < 4; ++m)
#pragma unroll
        for (int n = 0; n < 4; ++n)
#pragma unroll
            for (int j = 0; j < 4; ++j) {
                int row = erow + m * 16 + j, col = ecol + n * 16;
                float vv = acc[m][n][j];
                if constexpr (EPI == EPI_DIV) {
                    float* C = (float*)Cv + (long long)bb * cBatch;
                    C[(size_t)row * ldc + col] = vv * rsum[bb * SS + row];
                } else if constexpr (EPI == EPI_EXP) {
                    h16* C = (h16*)Cv + (long long)bb * cBatch;
                    C[(size_t)row * ldc + col] = (h16)__expf(vv - 16.0f);
                } else {
                    h16* C = (h16*)Cv + (long long)bb * cBatch;
                    C[(size_t)row * ldc + col] = (h16)vv;
                }
            }
}

// ---- reciprocal row sums of E (fp16 rows of length 2048); one block/row ----
__global__ __launch_bounds__(256) void rowsumE(const h16* __restrict__ sc,
                                               float* __restrict__ rsum) {
    const int row = blockIdx.x;
    const h16* rp = sc + (size_t)row * 2048;
    union { int4 i4; h16 h[8]; } u;
    u.i4 = ((const int4*)rp)[threadIdx.x];
    float s = 0.f;
#pragma unroll
    for (int j = 0; j < 8; ++j) s += (float)u.h[j];
#pragma unroll
    for (int off = 32; off; off >>= 1) s += __shfl_xor(s, off);
    __shared__ float ws[4];
    const int lane = threadIdx.x & 63, wid = threadIdx.x >> 6;
    if (lane == 0) ws[wid] = s;
    __syncthreads();
    if (threadIdx.x == 0)
        rsum[row] = 1.0f / (ws[0] + ws[1] + ws[2] + ws[3]);
}

extern "C" void kernel_launch(void* const* d_in, const int* in_sizes, int n_in,
                              void* d_out, int out_size, void* d_ws, size_t ws_size,
                              hipStream_t stream) {
    (void)in_sizes; (void)n_in; (void)out_size; (void)ws_size;
    const float* q = (const float*)d_in[0];
    const float* k = (const float*)d_in[1];
    const float* v = (const float*)d_in[2];
    const float* w = (const float*)d_in[3];
    float* out = (float*)d_out;

    const size_t QKV = (size_t)BB * SS * DD;
    h16* qh = (h16*)d_ws;            // 16 MB (reused as vpT after GEMM1 consumes q)
    h16* kh = qh + QKV;              // 16 MB
    h16* vh = kh + QKV;              // 16 MB
    h16* wh = vh + QKV;              // 2 MB
    h16* sc = wh + (size_t)DD * DD;  // E = exp(scores-16): 33.5 MB
    float* rsum = (float*)(sc + (size_t)BB * SS * SS);   // 32 KB reciprocal sums

    // 1) fused fp32 -> fp16 (8-deep MLP probe); scale 0.125 folded into q
    cvt_all<<<3200, 256, 0, stream>>>(q, k, v, w, qh, kh, vh, wh);

    // 2) GEMM1 + exp epilogue: E[b][q][k] = exp(sum_d qh*kh - 16)
    //    256x256 tiles: 8x8x4 = 256 wgs (1 block/CU)
    gemm2p<256, EPI_EXP><<<256, 512, 0, stream>>>(
        qh, kh, (void*)sc, DD, DD, SS, DD, /*tilesN=*/8, /*tilesMN=*/64,
        (long long)SS * DD, (long long)SS * DD, (long long)SS * SS, nullptr);

    // 3) reciprocal row sums (read-only; replaces in-place softmax)
    rowsumE<<<BB * SS, 256, 0, stream>>>(sc, rsum);

    // 4) GEMM2: vpT[e][s] = sum_d W[e,d]*V[s,d]; M=1024, N=8192, K=1024.
    //    128^2 tiles: 8x64 = 512 wgs, 2 blocks/CU
    h16* vpT = qh;
    gemm2p_sm<EPI_H16><<<512, 256, 0, stream>>>(
        wh, vh, (void*)vpT, DD, DD, BB * SS, DD, /*tilesN=*/64, /*tilesMN=*/512,
        0LL, 0LL, 0LL, nullptr);

    // 5) GEMM3 + normalize: Y[b][q][e] = (sum_k E*vpT) * rsum[b,q]
    //    M=2048/batch, N=1024, K=2048. 128^2 tiles: 16x8x4 = 512 wgs
    gemm2p_sm<EPI_DIV><<<512, 256, 0, stream>>>(
        sc, vpT, (void*)out, SS, BB * SS, DD, SS, /*tilesN=*/8, /*tilesMN=*/128,
        (long long)SS * SS, (long long)SS, (long long)SS * DD, rsum);
}

// Round 15
// 134.488 us; speedup vs baseline: 1.3386x; 1.0008x over previous
//
#include <hip/hip_runtime.h>
#include <hip/hip_fp16.h>
#include <stdint.h>

// ---- types ----
typedef _Float16 h16;
typedef _Float16 h16x8 __attribute__((ext_vector_type(8)));
typedef float f32x4 __attribute__((ext_vector_type(4)));

#define BB 4
#define SS 2048
#define DD 1024

// epilogue modes
#define EPI_H16 0
#define EPI_EXP 1
#define EPI_DIV 2

__device__ __forceinline__ void gload16(const void* g, void* l) {
    __builtin_amdgcn_global_load_lds(
        (const __attribute__((address_space(1))) uint32_t*)g,
        (__attribute__((address_space(3))) uint32_t*)l, 16, 0, 0);
}

// ---- fp32 -> fp16 convert for q (*0.125) and k only; 8-deep MLP ----
// blocks [0,1024) q, [1024,2048) k; 2048 float4 per block.
__global__ __launch_bounds__(256) void cvt_qk(
    const float* __restrict__ q, const float* __restrict__ k,
    h16* __restrict__ qh, h16* __restrict__ kh) {
    int b = blockIdx.x;
    const float* src; h16* dst; float sc = 1.0f;
    if (b < 1024)      { src = q; dst = qh; sc = 0.125f; }
    else               { src = k; dst = kh; b -= 1024; }
    size_t base = (size_t)b * 2048 + threadIdx.x;   // float4 index
    float4 a[8];
#pragma unroll
    for (int i = 0; i < 8; ++i) a[i] = ((const float4*)src)[base + (size_t)i * 256];
#pragma unroll
    for (int i = 0; i < 8; ++i) {
        union { int2 i2; h16 h[4]; } u;
        u.h[0] = (h16)(a[i].x * sc); u.h[1] = (h16)(a[i].y * sc);
        u.h[2] = (h16)(a[i].z * sc); u.h[3] = (h16)(a[i].w * sc);
        ((int2*)dst)[base + (size_t)i * 256] = u.i2;
    }
}

// ==== FUSED: GEMM1 (round-14 verified gemm2p<256,EPI_EXP> body) + cvt(v,w) ====
// Grid = 320 blocks x 512 thr. blockIdx < 64: grid-stride fp32->fp16 convert
// of v and w (GEMM1 doesn't read vh/wh -> no dependency). These blocks stream
// ~57MB under GEMM1's idle HBM (GEMM1 alone: 0.6 TB/s of 6.3 achievable).
// Block-level concurrency only: separate blocks = separate vmcnt queues, so
// the GEMM's counted-vmcnt ledger is untouched (rounds-10/11 hazard excluded).
__global__ __launch_bounds__(512, 2) void gemm1_fused(
    const h16* __restrict__ A, const h16* __restrict__ B, h16* __restrict__ C,
    const float* __restrict__ v, const float* __restrict__ w,
    h16* __restrict__ vh, h16* __restrict__ wh)
{
    constexpr int ABYTES = 256 * 128;
    constexpr int BBYTES = 256 * 128;
    constexpr int BUFB   = ABYTES + BBYTES;
    __shared__ __align__(1024) char lds[2 * BUFB];   // 128 KB (both paths)

    const int tid = threadIdx.x;

    if (blockIdx.x < 64) {
        // ---- cvt(v,w) path: 64 blocks x 512 thr, fully coalesced ----
        const int lane = blockIdx.x * 512 + tid;      // 32768 lanes
        // v: 2097152 float4 -> 64 iters; w: 262144 float4 -> 8 iters
#pragma unroll 4
        for (int i = 0; i < 64; ++i) {
            size_t g = (size_t)i * 32768 + lane;
            float4 a = ((const float4*)v)[g];
            union { int2 i2; h16 h[4]; } u;
            u.h[0] = (h16)a.x; u.h[1] = (h16)a.y; u.h[2] = (h16)a.z; u.h[3] = (h16)a.w;
            ((int2*)vh)[g] = u.i2;
        }
#pragma unroll
        for (int i = 0; i < 8; ++i) {
            size_t g = (size_t)i * 32768 + lane;
            float4 a = ((const float4*)w)[g];
            union { int2 i2; h16 h[4]; } u;
            u.h[0] = (h16)a.x; u.h[1] = (h16)a.y; u.h[2] = (h16)a.z; u.h[3] = (h16)a.w;
            ((int2*)wh)[g] = u.i2;
        }
        return;
    }

    // ---- GEMM path: bid in [0,256); swizzle over constant 256 wgs ----
    const int gid = blockIdx.x - 64;
    const int wgid = (gid & 7) * 32 + (gid >> 3);   // XCD swizzle, 256 wgs
    const int bb  = wgid / 64;                       // tilesMN = 64
    const int rem = wgid % 64;
    const int tm = rem / 8, tn = rem % 8;            // tilesN = 8
    const int row0 = tm * 256, col0 = tn * 256;

    const h16* Ab = A + (long long)bb * ((long long)SS * DD);
    const h16* Bb = B + (long long)bb * ((long long)SS * DD);

    const int lane = tid & 63, wid = tid >> 6;
    const int wm = wid >> 2, wn = wid & 3;
    const int frow = lane & 15, kq = lane >> 4;

    const int NT = DD >> 6;   // 16

    f32x4 acc[8][4];
#pragma unroll
    for (int m = 0; m < 8; ++m)
#pragma unroll
        for (int n = 0; n < 4; ++n) acc[m][n] = (f32x4){0.f, 0.f, 0.f, 0.f};

    char* l0 = (char*)lds;

    auto STAGE_B = [&](int kt, int buf) {
#pragma unroll
        for (int i = 0; i < 4; ++i) {
            int d = i * 512 + tid;
            int s = d & 7, r = d >> 3;
            int gg = s ^ (r & 7);
            gload16(Bb + (size_t)(col0 + r) * DD + kt + gg * 8,
                    l0 + buf * BUFB + ABYTES + (r * 8 + s) * 16);
        }
    };
    auto STAGE_AH = [&](int kt, int buf, int mh) {
#pragma unroll
        for (int i = 0; i < 2; ++i) {
            int d = i * 512 + tid;
            int s = d & 7, hr = d >> 3;
            int r = ((hr & ~63) << 1) + mh * 64 + (hr & 63);
            int gg = s ^ (r & 7);
            gload16(Ab + (size_t)(row0 + r) * DD + kt + gg * 8,
                    l0 + buf * BUFB + (r * 8 + s) * 16);
        }
    };
    auto READ_A = [&](int buf, int mh, h16x8 (&af)[4][2]) {
#pragma unroll
        for (int mm = 0; mm < 4; ++mm)
#pragma unroll
            for (int ks = 0; ks < 2; ++ks) {
                int r = wm * 128 + (mh * 4 + mm) * 16 + frow;
                int s = (ks * 4 + kq) ^ (r & 7);
                af[mm][ks] = *(const h16x8*)(l0 + buf * BUFB + (r * 8 + s) * 16);
            }
    };
    auto READ_B = [&](int buf, h16x8 (&bf)[4][2]) {
#pragma unroll
        for (int nn = 0; nn < 4; ++nn)
#pragma unroll
            for (int ks = 0; ks < 2; ++ks) {
                int r = wn * 64 + nn * 16 + frow;
                int s = (ks * 4 + kq) ^ (r & 7);
                bf[nn][ks] = *(const h16x8*)(l0 + buf * BUFB + ABYTES + (r * 8 + s) * 16);
            }
    };
    auto MFMA_H = [&](int mh, h16x8 (&af)[4][2], h16x8 (&bf)[4][2]) {
        __builtin_amdgcn_s_setprio(1);
#pragma unroll
        for (int ks = 0; ks < 2; ++ks)
#pragma unroll
            for (int mm = 0; mm < 4; ++mm)
#pragma unroll
                for (int nn = 0; nn < 4; ++nn)
                    acc[mh * 4 + mm][nn] =
                        __builtin_amdgcn_mfma_f32_16x16x32_f16(
                            af[mm][ks], bf[nn][ks], acc[mh * 4 + mm][nn], 0, 0, 0);
        __builtin_amdgcn_s_setprio(0);
    };

    STAGE_B(0, 0); STAGE_AH(0, 0, 0); STAGE_AH(0, 0, 1);
    asm volatile("s_waitcnt vmcnt(2)" ::: "memory");
    __builtin_amdgcn_s_barrier();

    h16x8 af[4][2], bf[4][2];

    for (int G = 0; G < NT; ++G) {
        const int buf = G & 1;
        const int kt1 = (G + 1) << 6;
        if (G + 1 < NT) {
            STAGE_B(kt1, buf ^ 1);
            STAGE_AH(kt1, buf ^ 1, 0);
            STAGE_AH(kt1, buf ^ 1, 1);
        }
        READ_A(buf, 0, af);
        READ_B(buf, bf);
        MFMA_H(0, af, bf);
        if (G + 1 < NT) asm volatile("s_waitcnt vmcnt(8)" ::: "memory");
        else            asm volatile("s_waitcnt vmcnt(0)" ::: "memory");
        __builtin_amdgcn_s_barrier();
        READ_A(buf, 1, af);
        MFMA_H(1, af, bf);
        if (G + 1 >= NT) break;
        asm volatile("s_waitcnt vmcnt(2)" ::: "memory");
        __builtin_amdgcn_s_barrier();
    }

    // ---- epilogue: E = exp(score - 16), fp16
    h16* Cb = C + (long long)bb * ((long long)SS * SS);
    const int erow = row0 + wm * 128 + (lane >> 4) * 4;
    const int ecol = col0 + wn * 64 + (lane & 15);
#pragma unroll
    for (int m = 0; m < 8; ++m)
#pragma unroll
        for (int n = 0; n < 4; ++n)
#pragma unroll
            for (int j = 0; j < 4; ++j)
                Cb[(size_t)(erow + m * 16 + j) * SS + (ecol + n * 16)] =
                    (h16)__expf(acc[m][n][j] - 16.0f);
}

// ==== small GEMM (round-6/12 verified): 128x128, 4 waves, 2 blocks/CU ====
template<int EPI>
__global__ __launch_bounds__(256, 2) void gemm2p_sm(
    const h16* __restrict__ A, const h16* __restrict__ B, void* __restrict__ Cv,
    int lda, int ldb, int ldc, int K, int tilesN, int tilesMN,
    long long aBatch, long long bBatch, long long cBatch, const float* __restrict__ rsum)
{
    constexpr int ABYTES = 128 * 128;
    constexpr int BBYTES = 128 * 128;
    constexpr int BUFB   = ABYTES + BBYTES;

    __shared__ __align__(1024) char lds[2 * BUFB];   // 64 KB

    const int tid = threadIdx.x;
    const int nwg = gridDim.x;
    const int bid = blockIdx.x;
    const int wgid = (bid & 7) * (nwg >> 3) + (bid >> 3);   // XCD swizzle
    const int bb  = wgid / tilesMN;
    const int rem = wgid % tilesMN;
    const int tm = rem / tilesN, tn = rem % tilesN;
    const int row0 = tm * 128, col0 = tn * 128;

    const h16* Ab = A + (long long)bb * aBatch;
    const h16* Bb = B + (long long)bb * bBatch;

    const int lane = tid & 63, wid = tid >> 6;
    const int wm = wid >> 1, wn = wid & 1;     // 2M x 2N, wave tile 64x64
    const int frow = lane & 15, kq = lane >> 4;

    const int NT = K >> 6;

    f32x4 acc[4][4];
#pragma unroll
    for (int m = 0; m < 4; ++m)
#pragma unroll
        for (int n = 0; n < 4; ++n) acc[m][n] = (f32x4){0.f, 0.f, 0.f, 0.f};

    char* l0 = (char*)lds;

    auto STAGE_B = [&](int kt, int buf) {
#pragma unroll
        for (int i = 0; i < 4; ++i) {
            int d = i * 256 + tid;
            int s = d & 7, r = d >> 3;
            int gg = s ^ (r & 7);
            gload16(Bb + (size_t)(col0 + r) * ldb + kt + gg * 8,
                    l0 + buf * BUFB + ABYTES + (r * 8 + s) * 16);
        }
    };
    auto STAGE_AH = [&](int kt, int buf, int mh) {
#pragma unroll
        for (int i = 0; i < 2; ++i) {
            int d = i * 256 + tid;
            int s = d & 7, hr = d >> 3;
            int r = ((hr & ~31) << 1) + mh * 32 + (hr & 31);
            int gg = s ^ (r & 7);
            gload16(Ab + (size_t)(row0 + r) * lda + kt + gg * 8,
                    l0 + buf * BUFB + (r * 8 + s) * 16);
        }
    };
    auto READ_A = [&](int buf, int mh, h16x8 (&af)[2][2]) {
#pragma unroll
        for (int mm = 0; mm < 2; ++mm)
#pragma unroll
            for (int ks = 0; ks < 2; ++ks) {
                int r = wm * 64 + (mh * 2 + mm) * 16 + frow;
                int s = (ks * 4 + kq) ^ (r & 7);
                af[mm][ks] = *(const h16x8*)(l0 + buf * BUFB + (r * 8 + s) * 16);
            }
    };
    auto READ_B = [&](int buf, h16x8 (&bf)[4][2]) {
#pragma unroll
        for (int nn = 0; nn < 4; ++nn)
#pragma unroll
            for (int ks = 0; ks < 2; ++ks) {
                int r = wn * 64 + nn * 16 + frow;
                int s = (ks * 4 + kq) ^ (r & 7);
                bf[nn][ks] = *(const h16x8*)(l0 + buf * BUFB + ABYTES + (r * 8 + s) * 16);
            }
    };
    auto MFMA_H = [&](int mh, h16x8 (&af)[2][2], h16x8 (&bf)[4][2]) {
        __builtin_amdgcn_s_setprio(1);
#pragma unroll
        for (int ks = 0; ks < 2; ++ks)
#pragma unroll
            for (int mm = 0; mm < 2; ++mm)
#pragma unroll
                for (int nn = 0; nn < 4; ++nn)
                    acc[mh * 2 + mm][nn] =
                        __builtin_amdgcn_mfma_f32_16x16x32_f16(
                            af[mm][ks], bf[nn][ks], acc[mh * 2 + mm][nn], 0, 0, 0);
        __builtin_amdgcn_s_setprio(0);
    };

    STAGE_B(0, 0); STAGE_AH(0, 0, 0); STAGE_AH(0, 0, 1);
    asm volatile("s_waitcnt vmcnt(2)" ::: "memory");
    __builtin_amdgcn_s_barrier();

    h16x8 af[2][2], bf[4][2];

    for (int G = 0; G < NT; ++G) {
        const int buf = G & 1;
        const int kt1 = (G + 1) << 6;
        if (G + 1 < NT) {
            STAGE_B(kt1, buf ^ 1);
            STAGE_AH(kt1, buf ^ 1, 0);
            STAGE_AH(kt1, buf ^ 1, 1);
        }
        READ_A(buf, 0, af);
        READ_B(buf, bf);
        MFMA_H(0, af, bf);
        if (G + 1 < NT) asm volatile("s_waitcnt vmcnt(8)" ::: "memory");
        else            asm volatile("s_waitcnt vmcnt(0)" ::: "memory");
        __builtin_amdgcn_s_barrier();
        READ_A(buf, 1, af);
        MFMA_H(1, af, bf);
        if (G + 1 >= NT) break;
        asm volatile("s_waitcnt vmcnt(2)" ::: "memory");
        __builtin_amdgcn_s_barrier();
    }

    const int erow = row0 + wm * 64 + (lane >> 4) * 4;
    const int ecol = col0 + wn * 64 + (lane & 15);
#pragma unroll
    for (int m = 0; m < 4; ++m)
#pragma unroll
        for (int n = 0; n < 4; ++n)
#pragma unroll
            for (int j = 0; j < 4; ++j) {
                int row = erow + m * 16 + j, col = ecol + n * 16;
                float vv = acc[m][n][j];
                if constexpr (EPI == EPI_DIV) {
                    float* C = (float*)Cv + (long long)bb * cBatch;
                    C[(size_t)row * ldc + col] = vv * rsum[bb * SS + row];
                } else if constexpr (EPI == EPI_EXP) {
                    h16* C = (h16*)Cv + (long long)bb * cBatch;
                    C[(size_t)row * ldc + col] = (h16)__expf(vv - 16.0f);
                } else {
                    h16* C = (h16*)Cv + (long long)bb * cBatch;
                    C[(size_t)row * ldc + col] = (h16)vv;
                }
            }
}

// ---- reciprocal row sums of E (fp16 rows of length 2048); one block/row ----
__global__ __launch_bounds__(256) void rowsumE(const h16* __restrict__ sc,
                                               float* __restrict__ rsum) {
    const int row = blockIdx.x;
    const h16* rp = sc + (size_t)row * 2048;
    union { int4 i4; h16 h[8]; } u;
    u.i4 = ((const int4*)rp)[threadIdx.x];
    float s = 0.f;
#pragma unroll
    for (int j = 0; j < 8; ++j) s += (float)u.h[j];
#pragma unroll
    for (int off = 32; off; off >>= 1) s += __shfl_xor(s, off);
    __shared__ float ws[4];
    const int lane = threadIdx.x & 63, wid = threadIdx.x >> 6;
    if (lane == 0) ws[wid] = s;
    __syncthreads();
    if (threadIdx.x == 0)
        rsum[row] = 1.0f / (ws[0] + ws[1] + ws[2] + ws[3]);
}

extern "C" void kernel_launch(void* const* d_in, const int* in_sizes, int n_in,
                              void* d_out, int out_size, void* d_ws, size_t ws_size,
                              hipStream_t stream) {
    (void)in_sizes; (void)n_in; (void)out_size; (void)ws_size;
    const float* q = (const float*)d_in[0];
    const float* k = (const float*)d_in[1];
    const float* v = (const float*)d_in[2];
    const float* w = (const float*)d_in[3];
    float* out = (float*)d_out;

    const size_t QKV = (size_t)BB * SS * DD;
    h16* qh = (h16*)d_ws;            // 16 MB (reused as vpT after GEMM1 consumes q)
    h16* kh = qh + QKV;              // 16 MB
    h16* vh = kh + QKV;              // 16 MB
    h16* wh = vh + QKV;              // 2 MB
    h16* sc = wh + (size_t)DD * DD;  // E = exp(scores-16): 33.5 MB
    float* rsum = (float*)(sc + (size_t)BB * SS * SS);   // 32 KB reciprocal sums

    // 1) fp32 -> fp16 for q,k only (0.125 folded into q)
    cvt_qk<<<2048, 256, 0, stream>>>(q, k, qh, kh);

    // 2) FUSED GEMM1 + cvt(v,w): 64 cvt blocks + 256 GEMM blocks.
    //    E[b][q][kk] = exp(sum_d qh*kh - 16); vh,wh produced concurrently.
    gemm1_fused<<<320, 512, 0, stream>>>(qh, kh, sc, v, w, vh, wh);

    // 3) reciprocal row sums (read-only)
    rowsumE<<<BB * SS, 256, 0, stream>>>(sc, rsum);

    // 4) GEMM2: vpT[e][s] = sum_d W[e,d]*V[s,d]; 128^2 tiles, 512 wgs, 2/CU
    h16* vpT = qh;
    gemm2p_sm<EPI_H16><<<512, 256, 0, stream>>>(
        wh, vh, (void*)vpT, DD, DD, BB * SS, DD, /*tilesN=*/64, /*tilesMN=*/512,
        0LL, 0LL, 0LL, nullptr);

    // 5) GEMM3 + normalize: Y = (E . vpT) * rsum
    gemm2p_sm<EPI_DIV><<<512, 256, 0, stream>>>(
        sc, vpT, (void*)out, SS, BB * SS, DD, SS, /*tilesN=*/8, /*tilesMN=*/128,
        (long long)SS * SS, (long long)SS, (long long)SS * DD, rsum);
}

// Round 16
// 131.083 us; speedup vs baseline: 1.3734x; 1.0260x over previous
//
#include <hip/hip_runtime.h>
#include <hip/hip_fp16.h>
#include <stdint.h>

// ---- types ----
typedef _Float16 h16;
typedef _Float16 h16x8 __attribute__((ext_vector_type(8)));
typedef float f32x4 __attribute__((ext_vector_type(4)));

#define BB 4
#define SS 2048
#define DD 1024

#define EPI_H16 0
#define EPI_DIV 2   // store fp32 C / rowsum[row]  (rowsum = raw row sums)

__device__ __forceinline__ void gload16(const void* g, void* l) {
    __builtin_amdgcn_global_load_lds(
        (const __attribute__((address_space(1))) uint32_t*)g,
        (__attribute__((address_space(3))) uint32_t*)l, 16, 0, 0);
}

// ---- fp32 -> fp16 convert for q (*0.125) and k; block 0 also zeroes rowsum ----
__global__ __launch_bounds__(256) void cvt_qk(
    const float* __restrict__ q, const float* __restrict__ k,
    h16* __restrict__ qh, h16* __restrict__ kh, float* __restrict__ rowsum) {
    if (blockIdx.x == 0) {
#pragma unroll
        for (int i = 0; i < 32; ++i) rowsum[threadIdx.x + i * 256] = 0.f;
    }
    int b = blockIdx.x;
    const float* src; h16* dst; float sc = 1.0f;
    if (b < 1024)      { src = q; dst = qh; sc = 0.125f; }
    else               { src = k; dst = kh; b -= 1024; }
    size_t base = (size_t)b * 2048 + threadIdx.x;
    float4 a[8];
#pragma unroll
    for (int i = 0; i < 8; ++i) a[i] = ((const float4*)src)[base + (size_t)i * 256];
#pragma unroll
    for (int i = 0; i < 8; ++i) {
        union { int2 i2; h16 h[4]; } u;
        u.h[0] = (h16)(a[i].x * sc); u.h[1] = (h16)(a[i].y * sc);
        u.h[2] = (h16)(a[i].z * sc); u.h[3] = (h16)(a[i].w * sc);
        ((int2*)dst)[base + (size_t)i * 256] = u.i2;
    }
}

__device__ __forceinline__ void cvt_store(h16* dst, size_t g, float4 a) {
    union { int2 i2; h16 h[4]; } u;
    u.h[0] = (h16)a.x; u.h[1] = (h16)a.y; u.h[2] = (h16)a.z; u.h[3] = (h16)a.w;
    ((int2*)dst)[g] = u.i2;
}

// ==== GEMM1 (round-12 verified gemm2p<256> body) + in-loop cvt(v,w) +
//      epilogue rowsum-atomics ====
// cvt ledger safety: cvt ops are issued BEFORE each iter's STAGE, so at the
// mid vmcnt(8) the in-flight set = Ah1(G)(2,oldest)+cvt(<=2)+stage(8); retiring
// to 8 always retires Ah1(G) regardless of compiler reordering of the plain
// cvt ops vs builtin stages. End vmcnt(2) keeps the 2 youngest (= Ah1(G+1)).
// Worst-case reorder costs pipelining, never correctness.
__global__ __launch_bounds__(512, 2) void gemm1f(
    const h16* __restrict__ A, const h16* __restrict__ B, h16* __restrict__ C,
    const float* __restrict__ v, const float* __restrict__ w,
    h16* __restrict__ vh, h16* __restrict__ wh, float* __restrict__ rowsum)
{
    constexpr int ABYTES = 256 * 128;
    constexpr int BUFB   = 2 * ABYTES;
    __shared__ __align__(1024) char lds[2 * BUFB];   // 128 KB

    const int tid = threadIdx.x;
    const int gid = blockIdx.x;                      // 0..255
    const size_t tidg = (size_t)gid * 512 + tid;     // 0..131071

    const int wgid = (gid & 7) * 32 + (gid >> 3);    // XCD swizzle (256 wgs)
    const int bb  = wgid / 64;
    const int rem = wgid % 64;
    const int tm = rem / 8, tn = rem % 8;
    const int row0 = tm * 256, col0 = tn * 256;

    const h16* Ab = A + (long long)bb * ((long long)SS * DD);
    const h16* Bb = B + (long long)bb * ((long long)SS * DD);

    const int lane = tid & 63, wid = tid >> 6;
    const int wm = wid >> 2, wn = wid & 3;
    const int frow = lane & 15, kq = lane >> 4;

    const int NT = DD >> 6;   // 16

    f32x4 acc[8][4];
#pragma unroll
    for (int m = 0; m < 8; ++m)
#pragma unroll
        for (int n = 0; n < 4; ++n) acc[m][n] = (f32x4){0.f, 0.f, 0.f, 0.f};

    char* l0 = (char*)lds;

    auto STAGE_B = [&](int kt, int buf) {
#pragma unroll
        for (int i = 0; i < 4; ++i) {
            int d = i * 512 + tid;
            int s = d & 7, r = d >> 3;
            int gg = s ^ (r & 7);
            gload16(Bb + (size_t)(col0 + r) * DD + kt + gg * 8,
                    l0 + buf * BUFB + ABYTES + (r * 8 + s) * 16);
        }
    };
    auto STAGE_AH = [&](int kt, int buf, int mh) {
#pragma unroll
        for (int i = 0; i < 2; ++i) {
            int d = i * 512 + tid;
            int s = d & 7, hr = d >> 3;
            int r = ((hr & ~63) << 1) + mh * 64 + (hr & 63);
            int gg = s ^ (r & 7);
            gload16(Ab + (size_t)(row0 + r) * DD + kt + gg * 8,
                    l0 + buf * BUFB + (r * 8 + s) * 16);
        }
    };
    auto READ_A = [&](int buf, int mh, h16x8 (&af)[4][2]) {
#pragma unroll
        for (int mm = 0; mm < 4; ++mm)
#pragma unroll
            for (int ks = 0; ks < 2; ++ks) {
                int r = wm * 128 + (mh * 4 + mm) * 16 + frow;
                int s = (ks * 4 + kq) ^ (r & 7);
                af[mm][ks] = *(const h16x8*)(l0 + buf * BUFB + (r * 8 + s) * 16);
            }
    };
    auto READ_B = [&](int buf, h16x8 (&bf)[4][2]) {
#pragma unroll
        for (int nn = 0; nn < 4; ++nn)
#pragma unroll
            for (int ks = 0; ks < 2; ++ks) {
                int r = wn * 64 + nn * 16 + frow;
                int s = (ks * 4 + kq) ^ (r & 7);
                bf[nn][ks] = *(const h16x8*)(l0 + buf * BUFB + ABYTES + (r * 8 + s) * 16);
            }
    };
    auto MFMA_H = [&](int mh, h16x8 (&af)[4][2], h16x8 (&bf)[4][2]) {
        __builtin_amdgcn_s_setprio(1);
#pragma unroll
        for (int ks = 0; ks < 2; ++ks)
#pragma unroll
            for (int mm = 0; mm < 4; ++mm)
#pragma unroll
                for (int nn = 0; nn < 4; ++nn)
                    acc[mh * 4 + mm][nn] =
                        __builtin_amdgcn_mfma_f32_16x16x32_f16(
                            af[mm][ks], bf[nn][ks], acc[mh * 4 + mm][nn], 0, 0, 0);
        __builtin_amdgcn_s_setprio(0);
    };

    // ---- prologue: w cvt (2 float4/thread, oldest ops) + stage tile 0
    {
        float4 w0 = ((const float4*)w)[tidg];
        float4 w1 = ((const float4*)w)[131072 + tidg];
        cvt_store(wh, tidg, w0);
        cvt_store(wh, 131072 + tidg, w1);
    }
    STAGE_B(0, 0); STAGE_AH(0, 0, 0); STAGE_AH(0, 0, 1);
    asm volatile("s_waitcnt vmcnt(2)" ::: "memory");
    __builtin_amdgcn_s_barrier();

    h16x8 af[4][2], bf[4][2];
    float4 vbuf;   // one-iter rotation: load at iter G, store at iter G+1

    for (int G = 0; G < NT; ++G) {
        const int buf = G & 1;
        const int kt1 = (G + 1) << 6;
        // in-loop cvt of v: 1 float4/thread/iter, issued BEFORE stage
        float4 vnew = ((const float4*)v)[(size_t)G * 131072 + tidg];
        if (G > 0) cvt_store(vh, (size_t)(G - 1) * 131072 + tidg, vbuf);
        vbuf = vnew;
        if (G + 1 < NT) {
            STAGE_B(kt1, buf ^ 1);
            STAGE_AH(kt1, buf ^ 1, 0);
            STAGE_AH(kt1, buf ^ 1, 1);
        }
        READ_A(buf, 0, af);
        READ_B(buf, bf);
        MFMA_H(0, af, bf);
        if (G + 1 < NT) asm volatile("s_waitcnt vmcnt(8)" ::: "memory");
        else            asm volatile("s_waitcnt vmcnt(0)" ::: "memory");
        __builtin_amdgcn_s_barrier();
        READ_A(buf, 1, af);
        MFMA_H(1, af, bf);
        if (G + 1 >= NT) break;
        asm volatile("s_waitcnt vmcnt(2)" ::: "memory");
        __builtin_amdgcn_s_barrier();
    }
    // flush last v pair
    cvt_store(vh, (size_t)(NT - 1) * 131072 + tidg, vbuf);

    // ---- epilogue: E = exp(score-16) + per-row sum atomics
    h16* Cb = C + (long long)bb * ((long long)SS * SS);
    float* rs = rowsum + bb * SS;
    const int erow = row0 + wm * 128 + (lane >> 4) * 4;
    const int ecol = col0 + wn * 64 + (lane & 15);
#pragma unroll
    for (int m = 0; m < 8; ++m)
#pragma unroll
        for (int j = 0; j < 4; ++j) {
            const int row = erow + m * 16 + j;
            float p = 0.f;
#pragma unroll
            for (int n = 0; n < 4; ++n) {
                float e = __expf(acc[m][n][j] - 16.0f);
                Cb[(size_t)row * SS + (ecol + n * 16)] = (h16)e;
                p += e;
            }
            p += __shfl_xor(p, 1);
            p += __shfl_xor(p, 2);
            p += __shfl_xor(p, 4);
            p += __shfl_xor(p, 8);
            if ((lane & 15) == 0) atomicAdd(&rs[row], p);
        }
}

// ==== small GEMM (round-6/12 verified): 128x128, 4 waves, 2 blocks/CU ====
template<int EPI>
__global__ __launch_bounds__(256, 2) void gemm2p_sm(
    const h16* __restrict__ A, const h16* __restrict__ B, void* __restrict__ Cv,
    int lda, int ldb, int ldc, int K, int tilesN, int tilesMN,
    long long aBatch, long long bBatch, long long cBatch, const float* __restrict__ rowsum)
{
    constexpr int ABYTES = 128 * 128;
    constexpr int BBYTES = 128 * 128;
    constexpr int BUFB   = ABYTES + BBYTES;

    __shared__ __align__(1024) char lds[2 * BUFB];   // 64 KB

    const int tid = threadIdx.x;
    const int nwg = gridDim.x;
    const int bid = blockIdx.x;
    const int wgid = (bid & 7) * (nwg >> 3) + (bid >> 3);   // XCD swizzle
    const int bb  = wgid / tilesMN;
    const int rem = wgid % tilesMN;
    const int tm = rem / tilesN, tn = rem % tilesN;
    const int row0 = tm * 128, col0 = tn * 128;

    const h16* Ab = A + (long long)bb * aBatch;
    const h16* Bb = B + (long long)bb * bBatch;

    const int lane = tid & 63, wid = tid >> 6;
    const int wm = wid >> 1, wn = wid & 1;
    const int frow = lane & 15, kq = lane >> 4;

    const int NT = K >> 6;

    f32x4 acc[4][4];
#pragma unroll
    for (int m = 0; m < 4; ++m)
#pragma unroll
        for (int n = 0; n < 4; ++n) acc[m][n] = (f32x4){0.f, 0.f, 0.f, 0.f};

    char* l0 = (char*)lds;

    auto STAGE_B = [&](int kt, int buf) {
#pragma unroll
        for (int i = 0; i < 4; ++i) {
            int d = i * 256 + tid;
            int s = d & 7, r = d >> 3;
            int gg = s ^ (r & 7);
            gload16(Bb + (size_t)(col0 + r) * ldb + kt + gg * 8,
                    l0 + buf * BUFB + ABYTES + (r * 8 + s) * 16);
        }
    };
    auto STAGE_AH = [&](int kt, int buf, int mh) {
#pragma unroll
        for (int i = 0; i < 2; ++i) {
            int d = i * 256 + tid;
            int s = d & 7, hr = d >> 3;
            int r = ((hr & ~31) << 1) + mh * 32 + (hr & 31);
            int gg = s ^ (r & 7);
            gload16(Ab + (size_t)(row0 + r) * lda + kt + gg * 8,
                    l0 + buf * BUFB + (r * 8 + s) * 16);
        }
    };
    auto READ_A = [&](int buf, int mh, h16x8 (&af)[2][2]) {
#pragma unroll
        for (int mm = 0; mm < 2; ++mm)
#pragma unroll
            for (int ks = 0; ks < 2; ++ks) {
                int r = wm * 64 + (mh * 2 + mm) * 16 + frow;
                int s = (ks * 4 + kq) ^ (r & 7);
                af[mm][ks] = *(const h16x8*)(l0 + buf * BUFB + (r * 8 + s) * 16);
            }
    };
    auto READ_B = [&](int buf, h16x8 (&bf)[4][2]) {
#pragma unroll
        for (int nn = 0; nn < 4; ++nn)
#pragma unroll
            for (int ks = 0; ks < 2; ++ks) {
                int r = wn * 64 + nn * 16 + frow;
                int s = (ks * 4 + kq) ^ (r & 7);
                bf[nn][ks] = *(const h16x8*)(l0 + buf * BUFB + ABYTES + (r * 8 + s) * 16);
            }
    };
    auto MFMA_H = [&](int mh, h16x8 (&af)[2][2], h16x8 (&bf)[4][2]) {
        __builtin_amdgcn_s_setprio(1);
#pragma unroll
        for (int ks = 0; ks < 2; ++ks)
#pragma unroll
            for (int mm = 0; mm < 2; ++mm)
#pragma unroll
                for (int nn = 0; nn < 4; ++nn)
                    acc[mh * 2 + mm][nn] =
                        __builtin_amdgcn_mfma_f32_16x16x32_f16(
                            af[mm][ks], bf[nn][ks], acc[mh * 2 + mm][nn], 0, 0, 0);
        __builtin_amdgcn_s_setprio(0);
    };

    STAGE_B(0, 0); STAGE_AH(0, 0, 0); STAGE_AH(0, 0, 1);
    asm volatile("s_waitcnt vmcnt(2)" ::: "memory");
    __builtin_amdgcn_s_barrier();

    h16x8 af[2][2], bf[4][2];

    for (int G = 0; G < NT; ++G) {
        const int buf = G & 1;
        const int kt1 = (G + 1) << 6;
        if (G + 1 < NT) {
            STAGE_B(kt1, buf ^ 1);
            STAGE_AH(kt1, buf ^ 1, 0);
            STAGE_AH(kt1, buf ^ 1, 1);
        }
        READ_A(buf, 0, af);
        READ_B(buf, bf);
        MFMA_H(0, af, bf);
        if (G + 1 < NT) asm volatile("s_waitcnt vmcnt(8)" ::: "memory");
        else            asm volatile("s_waitcnt vmcnt(0)" ::: "memory");
        __builtin_amdgcn_s_barrier();
        READ_A(buf, 1, af);
        MFMA_H(1, af, bf);
        if (G + 1 >= NT) break;
        asm volatile("s_waitcnt vmcnt(2)" ::: "memory");
        __builtin_amdgcn_s_barrier();
    }

    const int erow = row0 + wm * 64 + (lane >> 4) * 4;
    const int ecol = col0 + wn * 64 + (lane & 15);
#pragma unroll
    for (int m = 0; m < 4; ++m)
#pragma unroll
        for (int n = 0; n < 4; ++n)
#pragma unroll
            for (int j = 0; j < 4; ++j) {
                int row = erow + m * 16 + j, col = ecol + n * 16;
                float vv = acc[m][n][j];
                if constexpr (EPI == EPI_DIV) {
                    float* C = (float*)Cv + (long long)bb * cBatch;
                    C[(size_t)row * ldc + col] = vv / rowsum[bb * SS + row];
                } else {
                    h16* C = (h16*)Cv + (long long)bb * cBatch;
                    C[(size_t)row * ldc + col] = (h16)vv;
                }
            }
}

extern "C" void kernel_launch(void* const* d_in, const int* in_sizes, int n_in,
                              void* d_out, int out_size, void* d_ws, size_t ws_size,
                              hipStream_t stream) {
    (void)in_sizes; (void)n_in; (void)out_size; (void)ws_size;
    const float* q = (const float*)d_in[0];
    const float* k = (const float*)d_in[1];
    const float* v = (const float*)d_in[2];
    const float* w = (const float*)d_in[3];
    float* out = (float*)d_out;

    const size_t QKV = (size_t)BB * SS * DD;
    h16* qh = (h16*)d_ws;            // 16 MB (reused as vpT after GEMM1 consumes q)
    h16* kh = qh + QKV;              // 16 MB
    h16* vh = kh + QKV;              // 16 MB
    h16* wh = vh + QKV;              // 2 MB
    h16* sc = wh + (size_t)DD * DD;  // E = exp(scores-16): 33.5 MB
    float* rowsum = (float*)(sc + (size_t)BB * SS * SS);   // 32 KB raw row sums

    // 1) q,k fp32->fp16 (0.125 into q); block 0 zeroes rowsum
    cvt_qk<<<2048, 256, 0, stream>>>(q, k, qh, kh, rowsum);

    // 2) GEMM1 + in-loop cvt(v,w) + epilogue rowsum atomics
    gemm1f<<<256, 512, 0, stream>>>(qh, kh, sc, v, w, vh, wh, rowsum);

    // 3) GEMM2: vpT[e][s] = sum_d W[e,d]*V[s,d]; 128^2 tiles, 512 wgs, 2/CU
    h16* vpT = qh;
    gemm2p_sm<EPI_H16><<<512, 256, 0, stream>>>(
        wh, vh, (void*)vpT, DD, DD, BB * SS, DD, /*tilesN=*/64, /*tilesMN=*/512,
        0LL, 0LL, 0LL, nullptr);

    // 4) GEMM3 + normalize: Y = (E . vpT) / rowsum
    gemm2p_sm<EPI_DIV><<<512, 256, 0, stream>>>(
        sc, vpT, (void*)out, SS, BB * SS, DD, SS, /*tilesN=*/8, /*tilesMN=*/128,
        (long long)SS * SS, (long long)SS, (long long)SS * DD, rowsum);
}